// Round 17
// baseline (2494.628 us; speedup 1.0000x reference)
//
#include <hip/hip_runtime.h>
#include <hip/hip_bf16.h>

#define T_LEN 512
#define B_SZ  64
#define D_SZ  1024

typedef __attribute__((ext_vector_type(8))) short  short8;   // 8 bf16
typedef __attribute__((ext_vector_type(4))) float  f32x4;
typedef __attribute__((ext_vector_type(4))) unsigned short ushort4v;
typedef __attribute__((ext_vector_type(4))) unsigned int   uint4v;

__device__ __forceinline__ float bf2f(unsigned short u) {
    unsigned int x = ((unsigned int)u) << 16;
    return __uint_as_float(x);
}
__device__ __forceinline__ unsigned short f2bf(float f) {
    unsigned int x = __float_as_uint(f);
    unsigned int r = x + 0x7FFFu + ((x >> 16) & 1u);   // round-to-nearest-even
    return (unsigned short)(r >> 16);
}
__device__ __forceinline__ void split2p(float f, unsigned short* hi, unsigned short* lo) {
    unsigned short h = f2bf(f);
    *hi = h;
    *lo = f2bf(f - bf2f(h));
}
// fast tanh: (e^2x - 1)/(e^2x + 1); clamp +-20 guards inf/inf=NaN; err ~1e-6
__device__ __forceinline__ float fast_tanh(float x) {
    float xx = fminf(fmaxf(x, -20.0f), 20.0f);
    float e2 = __expf(2.0f * xx);
    return __fdividef(e2 - 1.0f, e2 + 1.0f);
}

// ---------------------------------------------------------------------------
// Sync: slot[8 teams][64] -- one int PER WAVE (4 waves x 16 wgs). 256B/team.
// Stores only (no RMW). Slot index = c*4+wave, so slots 0..31 are exactly
// the producers of cols 0..511 (c=0..7) -- the k-split poll exploits this.
// ---------------------------------------------------------------------------
#define CNT_STRIDE 64

__global__ void init_kernel(int* slot) {
    int i = threadIdx.x;
    if (i < 8 * CNT_STRIDE) slot[i] = 0;
}

// ---------------------------------------------------------------------------
// Kernel B: xproj = x @ W_ih^T + b_ih (fp32 out), split-precision bf16 MFMA.
// (unchanged from R8)
// ---------------------------------------------------------------------------
#define BM 128
#define BN 128
#define BK 32
#define ASTR (BK + 8)

__global__ __launch_bounds__(256) void xproj_kernel(
    const float* __restrict__ x, const float* __restrict__ Wih,
    const float* __restrict__ bih, float* __restrict__ xp)
{
    __shared__ unsigned short Ah[BM][ASTR];
    __shared__ unsigned short Al[BM][ASTR];
    __shared__ unsigned short Bh[BN][ASTR];
    __shared__ unsigned short Bl[BN][ASTR];

    const int nblk = D_SZ / BN;
    const int bm = blockIdx.x / nblk;
    const int bn = blockIdx.x % nblk;
    const int m0 = bm * BM, n0 = bn * BN;
    const int tid  = threadIdx.x;
    const int lane = tid & 63, wave = tid >> 6;
    const int wm = wave >> 1, wn = wave & 1;

    f32x4 acc[4][4];
#pragma unroll
    for (int i = 0; i < 4; i++)
#pragma unroll
        for (int j = 0; j < 4; j++) acc[i][j] = (f32x4)0.0f;

    const int ar = lane & 15;
    const int kb = (lane >> 4) << 3;

    for (int k0 = 0; k0 < D_SZ; k0 += BK) {
#pragma unroll
        for (int i = 0; i < 4; i++) {
            int f4  = tid + i * 256;
            int row = f4 >> 3;
            int c4  = (f4 & 7) << 2;
            f32x4 va = *reinterpret_cast<const f32x4*>(x   + (size_t)(m0 + row) * D_SZ + k0 + c4);
            f32x4 vb = *reinterpret_cast<const f32x4*>(Wih + (size_t)(n0 + row) * D_SZ + k0 + c4);
            ushort4v pah, pal, pbh, pbl;
#pragma unroll
            for (int e = 0; e < 4; e++) {
                unsigned short h_, l_;
                split2p(va[e], &h_, &l_); pah[e] = h_; pal[e] = l_;
                split2p(vb[e], &h_, &l_); pbh[e] = h_; pbl[e] = l_;
            }
            *reinterpret_cast<ushort4v*>(&Ah[row][c4]) = pah;
            *reinterpret_cast<ushort4v*>(&Al[row][c4]) = pal;
            *reinterpret_cast<ushort4v*>(&Bh[row][c4]) = pbh;
            *reinterpret_cast<ushort4v*>(&Bl[row][c4]) = pbl;
        }
        __syncthreads();

        short8 ah[4], al[4], bh[4], bl[4];
#pragma unroll
        for (int mi = 0; mi < 4; mi++) {
            ah[mi] = *reinterpret_cast<const short8*>(&Ah[wm * 64 + mi * 16 + ar][kb]);
            al[mi] = *reinterpret_cast<const short8*>(&Al[wm * 64 + mi * 16 + ar][kb]);
        }
#pragma unroll
        for (int ni = 0; ni < 4; ni++) {
            bh[ni] = *reinterpret_cast<const short8*>(&Bh[wn * 64 + ni * 16 + ar][kb]);
            bl[ni] = *reinterpret_cast<const short8*>(&Bl[wn * 64 + ni * 16 + ar][kb]);
        }
#pragma unroll
        for (int mi = 0; mi < 4; mi++)
#pragma unroll
            for (int ni = 0; ni < 4; ni++) {
                acc[mi][ni] = __builtin_amdgcn_mfma_f32_16x16x32_bf16(ah[mi], bh[ni], acc[mi][ni], 0, 0, 0);
                acc[mi][ni] = __builtin_amdgcn_mfma_f32_16x16x32_bf16(al[mi], bh[ni], acc[mi][ni], 0, 0, 0);
                acc[mi][ni] = __builtin_amdgcn_mfma_f32_16x16x32_bf16(ah[mi], bl[ni], acc[mi][ni], 0, 0, 0);
            }
        __syncthreads();
    }

    const int r0 = (lane >> 4) * 4;
    const int cl = lane & 15;
#pragma unroll
    for (int mi = 0; mi < 4; mi++) {
#pragma unroll
        for (int ni = 0; ni < 4; ni++) {
            int col = n0 + wn * 64 + ni * 16 + cl;
            float bias = bih[col];
            size_t base = (size_t)(m0 + wm * 64 + mi * 16 + r0) * D_SZ + col;
#pragma unroll
            for (int r = 0; r < 4; r++)
                xp[base + (size_t)r * D_SZ] = acc[mi][ni][r] + bias;
        }
    }
}

// ---------------------------------------------------------------------------
// Kernel C: persistent recurrence, K-SPLIT DEPENDENCY PIPELINE.
// 128 wgs = 8 teams x 16 wgs x 256 thr (4 waves, 64 cols each).
// Phase 1: poll slots 0..31 (producers of cols<512) + OWN wg's 4 slots
//   (sibling-ordering: sibling published t => finished step t-1's LDS reads;
//   phase-1 writes cols<512, disjoint from a sibling still in kk16..31)
//   -> load+unpack cols<512 -> barrier -> MFMA kk0..15 (Wlo in registers).
// Phase 2: poll all 64 -> load+unpack cols>=512 -> barrier -> MFMA kk16..31.
// Staging starts at max(32 producers) not max(64); straggler wait overlaps
// lower-half MFMA. Everything else = R15 (per-wave publish after per-wave
// vmcnt drain, out-stores after publish, fast_tanh, wl_r).
// SQ_LDS_BANK_CONFLICT ~8.4e7 is intrinsic ds_read_b128 cost (4cyc, m134).
// ---------------------------------------------------------------------------
#define MR 8
#define NC 64
#define HSTR (D_SZ + 8)
#define WSTR 520

__global__ __launch_bounds__(256, 1) void rnn_kernel(
    const float* __restrict__ xp, const float* __restrict__ Whh,
    const float* __restrict__ bhh, float* __restrict__ out,
    unsigned int* hbuf, int* slot)
{
    __shared__ unsigned short Hh[16][HSTR];
    __shared__ unsigned short Hl[16][HSTR];
    __shared__ unsigned short Wlo[4][16][WSTR];   // kk 16..31 only, per wave

    const int wg = blockIdx.x;
    const int b  = wg & 7;        // team
    const int c  = wg >> 3;       // 0..15, 64-col group
    const int tid  = threadIdx.x;
    const int lane = tid & 63, wave = tid >> 6;   // wave 0..3

    const int cl   = lane & 15;
    const int hi4  = lane >> 4;
    const int kb   = hi4 << 3;
    const int colg = c * NC + wave * 16 + cl;
    const float bias = bhh[colg];
    const int rloc = hi4 * 4;
    const bool active = (hi4 < 2);

    int* tslot = slot + b * CNT_STRIDE;
    const int myslot = c * 4 + wave;
    // phase-1 requirement: lower 32 producers + own wg's 4 waves
    const unsigned long long need1 = 0xFFFFFFFFull | (0xFull << (c * 4));

    // W_hh slice: hi plane -> registers; lo kk<16 -> registers, kk>=16 -> LDS
    short8 wh[32], wl_r[16];
    {
        const float* wrow = Whh + (size_t)colg * D_SZ;
#pragma unroll
        for (int kk = 0; kk < 32; kk++) {
            f32x4 v0 = *reinterpret_cast<const f32x4*>(wrow + kk * 32 + kb);
            f32x4 v1 = *reinterpret_cast<const f32x4*>(wrow + kk * 32 + kb + 4);
            short8 sh, sl;
#pragma unroll
            for (int e = 0; e < 4; e++) {
                unsigned short h_, l_;
                split2p(v0[e], &h_, &l_); sh[e] = (short)h_; sl[e] = (short)l_;
                split2p(v1[e], &h_, &l_); sh[4 + e] = (short)h_; sl[4 + e] = (short)l_;
            }
            wh[kk] = sh;
            if (kk < 16) wl_r[kk] = sl;
            else *reinterpret_cast<short8*>(&Wlo[wave][cl][(kk - 16) * 32 + kb]) = sl;
        }
    }
    for (int i = tid; i < 16 * HSTR; i += 256) {
        (&Hh[0][0])[i] = 0;
        (&Hl[0][0])[i] = 0;
    }
    __syncthreads();

    for (int t = 0; t < T_LEN; t++) {
        // ---- prefetch this step's xp values (independent of h) ----
        float xv[4];
        const float* xpt = xp + ((size_t)t * B_SZ + b * MR) * D_SZ;
        if (active) {
#pragma unroll
            for (int r = 0; r < 4; r++)
                xv[r] = xpt[(size_t)(rloc + r) * D_SZ + colg];
        }

        const uint4v* hsrc16 = reinterpret_cast<const uint4v*>(
            hbuf + ((size_t)(t & 1) * B_SZ + b * MR) * D_SZ);

        if (t > 0) {
            // ---- PHASE 1 poll: lower-half producers + own wg ----
            for (int tries = 0; tries < 400000; ++tries) {
                int v = __hip_atomic_load(tslot + lane, __ATOMIC_RELAXED, __HIP_MEMORY_SCOPE_AGENT);
                unsigned long long rdy = __ballot(v >= t);
                if ((rdy & need1) == need1) break;
            }
            // ---- stage cols<512: 4 uint4/thread, one round trip ----
            uint4v vv[4];
#pragma unroll
            for (int i = 0; i < 4; i++) {
                int jh = tid + i * 256;                     // 0..1023
                int ti = ((jh >> 7) << 8) + (jh & 127);     // row*256 + col4
                asm volatile("global_load_dwordx4 %0, %1, off sc0 sc1"
                             : "=v"(vv[i]) : "v"(hsrc16 + ti) : "memory");
            }
            asm volatile("s_waitcnt vmcnt(0)" ::: "memory");
            __builtin_amdgcn_sched_barrier(0);
#pragma unroll
            for (int i = 0; i < 4; i++) {
                int jh  = tid + i * 256;
                int row = jh >> 7;
                int c4  = (jh & 127) << 2;                  // 0..508
                ushort4v hh, hl;
#pragma unroll
                for (int e = 0; e < 4; e++) {
                    unsigned int u = vv[i][e];
                    hh[e] = (unsigned short)(u & 0xFFFFu);
                    hl[e] = (unsigned short)(u >> 16);
                }
                *reinterpret_cast<ushort4v*>(&Hh[row][c4]) = hh;
                *reinterpret_cast<ushort4v*>(&Hl[row][c4]) = hl;
            }
            __syncthreads();   // cols<512 staged
        }

        // ---- MFMA kk 0..15 (k<512), Wlo from registers ----
        f32x4 a0 = (f32x4)0.0f, a1 = (f32x4)0.0f, a2 = (f32x4)0.0f;
#pragma unroll
        for (int kk = 0; kk < 16; kk++) {
            short8 ah  = *reinterpret_cast<const short8*>(&Hh[cl][kk * 32 + kb]);
            short8 alo = *reinterpret_cast<const short8*>(&Hl[cl][kk * 32 + kb]);
            a0 = __builtin_amdgcn_mfma_f32_16x16x32_bf16(ah,  wh[kk],   a0, 0, 0, 0);
            a1 = __builtin_amdgcn_mfma_f32_16x16x32_bf16(alo, wh[kk],   a1, 0, 0, 0);
            a2 = __builtin_amdgcn_mfma_f32_16x16x32_bf16(ah,  wl_r[kk], a2, 0, 0, 0);
        }

        if (t > 0) {
            // ---- PHASE 2 poll: everyone (upper producers likely done) ----
            for (int tries = 0; tries < 400000; ++tries) {
                int v = __hip_atomic_load(tslot + lane, __ATOMIC_RELAXED, __HIP_MEMORY_SCOPE_AGENT);
                unsigned long long rdy = __ballot(v >= t);
                if (rdy == ~0ull) break;
            }
            // ---- stage cols>=512 ----
            uint4v vv[4];
#pragma unroll
            for (int i = 0; i < 4; i++) {
                int jh = tid + i * 256;
                int ti = ((jh >> 7) << 8) + 128 + (jh & 127);
                asm volatile("global_load_dwordx4 %0, %1, off sc0 sc1"
                             : "=v"(vv[i]) : "v"(hsrc16 + ti) : "memory");
            }
            asm volatile("s_waitcnt vmcnt(0)" ::: "memory");
            __builtin_amdgcn_sched_barrier(0);
#pragma unroll
            for (int i = 0; i < 4; i++) {
                int jh  = tid + i * 256;
                int row = jh >> 7;
                int c4  = 512 + ((jh & 127) << 2);          // 512..1020
                ushort4v hh, hl;
#pragma unroll
                for (int e = 0; e < 4; e++) {
                    unsigned int u = vv[i][e];
                    hh[e] = (unsigned short)(u & 0xFFFFu);
                    hl[e] = (unsigned short)(u >> 16);
                }
                *reinterpret_cast<ushort4v*>(&Hh[row][c4]) = hh;
                *reinterpret_cast<ushort4v*>(&Hl[row][c4]) = hl;
            }
            __syncthreads();   // cols>=512 staged
        }

        // ---- MFMA kk 16..31 (k>=512), Wlo from LDS ----
#pragma unroll
        for (int kk = 16; kk < 32; kk++) {
            short8 ah  = *reinterpret_cast<const short8*>(&Hh[cl][kk * 32 + kb]);
            short8 alo = *reinterpret_cast<const short8*>(&Hl[cl][kk * 32 + kb]);
            short8 wlv = *reinterpret_cast<const short8*>(&Wlo[wave][cl][(kk - 16) * 32 + kb]);
            a0 = __builtin_amdgcn_mfma_f32_16x16x32_bf16(ah,  wh[kk], a0, 0, 0, 0);
            a1 = __builtin_amdgcn_mfma_f32_16x16x32_bf16(alo, wh[kk], a1, 0, 0, 0);
            a2 = __builtin_amdgcn_mfma_f32_16x16x32_bf16(ah,  wlv,    a2, 0, 0, 0);
        }

        float hval[4];
        if (active) {
            unsigned int* hdst = hbuf + ((size_t)((t + 1) & 1) * B_SZ + b * MR) * D_SZ;
#pragma unroll
            for (int r = 0; r < 4; r++) {
                int row = rloc + r;
                float pre = (a0[r] + a1[r] + a2[r]) + xv[r] + bias;
                float h = fast_tanh(pre);
                hval[r] = h;
                unsigned short hh_, ll_;
                split2p(h, &hh_, &ll_);
                unsigned int packed = (unsigned int)hh_ | ((unsigned int)ll_ << 16);
                __hip_atomic_store(&hdst[(size_t)row * D_SZ + colg], packed,
                                   __ATOMIC_RELAXED, __HIP_MEMORY_SCOPE_AGENT);
            }
        }
        // per-wave drain, then per-wave publish (no barrier)
        asm volatile("s_waitcnt vmcnt(0)" ::: "memory");
        if (lane == 0)
            __hip_atomic_store(tslot + myslot, t + 1, __ATOMIC_RELAXED, __HIP_MEMORY_SCOPE_AGENT);

        // out stores AFTER publish: off the inter-team critical path
        if (active) {
            float* outt = out + ((size_t)t * B_SZ + b * MR) * D_SZ;
#pragma unroll
            for (int r = 0; r < 4; r++) {
                int row = rloc + r;
                outt[(size_t)row * D_SZ + colg] = hval[r];
                if (t == T_LEN - 1)
                    out[(size_t)T_LEN * B_SZ * D_SZ + (size_t)(b * MR + row) * D_SZ + colg] = hval[r];
            }
        }
    }
}

// ---------------------------------------------------------------------------
extern "C" void kernel_launch(void* const* d_in, const int* in_sizes, int n_in,
                              void* d_out, int out_size, void* d_ws, size_t ws_size,
                              hipStream_t stream)
{
    const float* x   = (const float*)d_in[0];
    const float* Wih = (const float*)d_in[1];
    const float* Whh = (const float*)d_in[2];
    const float* bih = (const float*)d_in[3];
    const float* bhh = (const float*)d_in[4];
    float* out = (float*)d_out;

    char* ws = (char*)d_ws;
    float*        xp   = (float*)ws;                        // 134217728 B
    unsigned int* hbuf = (unsigned int*)(ws + 134217728);   // 524288 B
    int*          slot = (int*)(ws + 134217728 + 524288);   // 512 ints

    init_kernel<<<dim3(1), dim3(512), 0, stream>>>(slot);
    xproj_kernel<<<dim3(2048), dim3(256), 0, stream>>>(x, Wih, bih, xp);
    rnn_kernel<<<dim3(128), dim3(256), 0, stream>>>(xp, Whh, bhh, out, hbuf, slot);
}

// Round 18
// 2209.352 us; speedup vs baseline: 1.1291x; 1.1291x over previous
//
#include <hip/hip_runtime.h>
#include <hip/hip_bf16.h>

#define T_LEN 512
#define B_SZ  64
#define D_SZ  1024

typedef __attribute__((ext_vector_type(8))) short  short8;   // 8 bf16
typedef __attribute__((ext_vector_type(4))) float  f32x4;
typedef __attribute__((ext_vector_type(4))) unsigned short ushort4v;
typedef __attribute__((ext_vector_type(4))) unsigned int   uint4v;

__device__ __forceinline__ float bf2f(unsigned short u) {
    unsigned int x = ((unsigned int)u) << 16;
    return __uint_as_float(x);
}
__device__ __forceinline__ unsigned short f2bf(float f) {
    unsigned int x = __float_as_uint(f);
    unsigned int r = x + 0x7FFFu + ((x >> 16) & 1u);   // round-to-nearest-even
    return (unsigned short)(r >> 16);
}
__device__ __forceinline__ void split2p(float f, unsigned short* hi, unsigned short* lo) {
    unsigned short h = f2bf(f);
    *hi = h;
    *lo = f2bf(f - bf2f(h));
}

// ---------------------------------------------------------------------------
// Sync layout: 8 teams x 64 ints (256 B) -> each team's 32 producer slots
// live in their own cacheline; no cross-team line sharing, no RMWs ever.
// ---------------------------------------------------------------------------
#define CNT_STRIDE 64

__global__ void init_kernel(int* slot) {
    int i = threadIdx.x;
    if (i < 8 * CNT_STRIDE) slot[i] = 0;
}

// ---------------------------------------------------------------------------
// Kernel B: xproj = x @ W_ih^T + b_ih (fp32 out), split-precision bf16 MFMA.
// ---------------------------------------------------------------------------
#define BM 128
#define BN 128
#define BK 32
#define ASTR (BK + 8)

__global__ __launch_bounds__(256) void xproj_kernel(
    const float* __restrict__ x, const float* __restrict__ Wih,
    const float* __restrict__ bih, float* __restrict__ xp)
{
    __shared__ unsigned short Ah[BM][ASTR];
    __shared__ unsigned short Al[BM][ASTR];
    __shared__ unsigned short Bh[BN][ASTR];
    __shared__ unsigned short Bl[BN][ASTR];

    const int nblk = D_SZ / BN;
    const int bm = blockIdx.x / nblk;
    const int bn = blockIdx.x % nblk;
    const int m0 = bm * BM, n0 = bn * BN;
    const int tid  = threadIdx.x;
    const int lane = tid & 63, wave = tid >> 6;
    const int wm = wave >> 1, wn = wave & 1;

    f32x4 acc[4][4];
#pragma unroll
    for (int i = 0; i < 4; i++)
#pragma unroll
        for (int j = 0; j < 4; j++) acc[i][j] = (f32x4)0.0f;

    const int ar = lane & 15;
    const int kb = (lane >> 4) << 3;

    for (int k0 = 0; k0 < D_SZ; k0 += BK) {
#pragma unroll
        for (int i = 0; i < 4; i++) {
            int f4  = tid + i * 256;
            int row = f4 >> 3;
            int c4  = (f4 & 7) << 2;
            f32x4 va = *reinterpret_cast<const f32x4*>(x   + (size_t)(m0 + row) * D_SZ + k0 + c4);
            f32x4 vb = *reinterpret_cast<const f32x4*>(Wih + (size_t)(n0 + row) * D_SZ + k0 + c4);
            ushort4v pah, pal, pbh, pbl;
#pragma unroll
            for (int e = 0; e < 4; e++) {
                unsigned short h_, l_;
                split2p(va[e], &h_, &l_); pah[e] = h_; pal[e] = l_;
                split2p(vb[e], &h_, &l_); pbh[e] = h_; pbl[e] = l_;
            }
            *reinterpret_cast<ushort4v*>(&Ah[row][c4]) = pah;
            *reinterpret_cast<ushort4v*>(&Al[row][c4]) = pal;
            *reinterpret_cast<ushort4v*>(&Bh[row][c4]) = pbh;
            *reinterpret_cast<ushort4v*>(&Bl[row][c4]) = pbl;
        }
        __syncthreads();

        short8 ah[4], al[4], bh[4], bl[4];
#pragma unroll
        for (int mi = 0; mi < 4; mi++) {
            ah[mi] = *reinterpret_cast<const short8*>(&Ah[wm * 64 + mi * 16 + ar][kb]);
            al[mi] = *reinterpret_cast<const short8*>(&Al[wm * 64 + mi * 16 + ar][kb]);
        }
#pragma unroll
        for (int ni = 0; ni < 4; ni++) {
            bh[ni] = *reinterpret_cast<const short8*>(&Bh[wn * 64 + ni * 16 + ar][kb]);
            bl[ni] = *reinterpret_cast<const short8*>(&Bl[wn * 64 + ni * 16 + ar][kb]);
        }
#pragma unroll
        for (int mi = 0; mi < 4; mi++)
#pragma unroll
            for (int ni = 0; ni < 4; ni++) {
                acc[mi][ni] = __builtin_amdgcn_mfma_f32_16x16x32_bf16(ah[mi], bh[ni], acc[mi][ni], 0, 0, 0);
                acc[mi][ni] = __builtin_amdgcn_mfma_f32_16x16x32_bf16(al[mi], bh[ni], acc[mi][ni], 0, 0, 0);
                acc[mi][ni] = __builtin_amdgcn_mfma_f32_16x16x32_bf16(ah[mi], bl[ni], acc[mi][ni], 0, 0, 0);
            }
        __syncthreads();
    }

    const int r0 = (lane >> 4) * 4;
    const int cl = lane & 15;
#pragma unroll
    for (int mi = 0; mi < 4; mi++) {
#pragma unroll
        for (int ni = 0; ni < 4; ni++) {
            int col = n0 + wn * 64 + ni * 16 + cl;
            float bias = bih[col];
            size_t base = (size_t)(m0 + wm * 64 + mi * 16 + r0) * D_SZ + col;
#pragma unroll
            for (int r = 0; r < 4; r++)
                xp[base + (size_t)r * D_SZ] = acc[mi][ni][r] + bias;
        }
    }
}

// ---------------------------------------------------------------------------
// Kernel C: persistent recurrence — R8 configuration (measured best: 1.95ms).
// 256 wgs = 8 teams (8 batch rows, padded to 16) x 32 col groups (32 cols),
// 128 threads/wg. W-hi in VGPRs (128), W-lo in LDS. h staged with 16
// coherent dwordx4 loads (sc0 sc1) issued back-to-back -> ONE MALL round
// trip; unpack split vmcnt(8)/vmcnt(0). wg-level publish: stores -> vmcnt(0)
// -> barrier -> tid0 slot store. out stores after publish. This is the best
// of 6 structural variants (R12/R13/R15/R17 all 2.0-2.2ms); the ~3.8us step
// is the structural handshake chain: compute ~1.2, drain ~0.4, publish ~0.3,
// detect ~0.4, 32KB broadcast RT ~0.6, unpack+barriers ~0.4, skew remainder.
// SQ_LDS_BANK_CONFLICT ~1e8 is intrinsic ds_read_b128 cost (4cyc, m134).
// ---------------------------------------------------------------------------
#define MR 8
#define NC 32
#define HSTR (D_SZ + 8)

__global__ __launch_bounds__(128, 1) void rnn_kernel(
    const float* __restrict__ xp, const float* __restrict__ Whh,
    const float* __restrict__ bhh, float* __restrict__ out,
    unsigned int* hbuf, int* slot)
{
    __shared__ unsigned short Hh[16][HSTR];
    __shared__ unsigned short Hl[16][HSTR];
    __shared__ unsigned short Wlo[2][16][HSTR];   // per-wave 16-col W-lo plane

    const int wg = blockIdx.x;
    const int b  = wg & 7;      // team (batch group)
    const int c  = wg >> 3;     // col group
    const int tid  = threadIdx.x;
    const int lane = tid & 63, wave = tid >> 6;

    const int cl   = lane & 15;
    const int hi4  = lane >> 4;
    const int kb   = hi4 << 3;
    const int colg = c * NC + wave * 16 + cl;
    const float bias = bhh[colg];
    const int rloc = hi4 * 4;
    const bool active = (hi4 < 2);

    int* tslot = slot + b * CNT_STRIDE;

    // W_hh slice: hi plane -> registers (128 VGPR), lo plane -> LDS
    short8 wh[32];
    {
        const float* wrow = Whh + (size_t)colg * D_SZ;
#pragma unroll
        for (int kk = 0; kk < 32; kk++) {
            f32x4 v0 = *reinterpret_cast<const f32x4*>(wrow + kk * 32 + kb);
            f32x4 v1 = *reinterpret_cast<const f32x4*>(wrow + kk * 32 + kb + 4);
            short8 sh, sl;
#pragma unroll
            for (int e = 0; e < 4; e++) {
                unsigned short h_, l_;
                split2p(v0[e], &h_, &l_); sh[e] = (short)h_; sl[e] = (short)l_;
                split2p(v1[e], &h_, &l_); sh[4 + e] = (short)h_; sl[4 + e] = (short)l_;
            }
            wh[kk] = sh;
            *reinterpret_cast<short8*>(&Wlo[wave][cl][kk * 32 + kb]) = sl;
        }
    }
    for (int i = tid; i < 16 * HSTR; i += 128) {
        (&Hh[0][0])[i] = 0;
        (&Hl[0][0])[i] = 0;
    }
    __syncthreads();

    for (int t = 0; t < T_LEN; t++) {
        // ---- prefetch this step's xp values (independent of h) ----
        float xv[4];
        const float* xpt = xp + ((size_t)t * B_SZ + b * MR) * D_SZ;
        if (active) {
#pragma unroll
            for (int r = 0; r < 4; r++)
                xv[r] = xpt[(size_t)(rloc + r) * D_SZ + colg];
        }

        if (t > 0) {
            // wave 0 polls the team line: one coalesced 128B load + ballot
            if (wave == 0) {
                for (long it = 0; it < 200000000L; ++it) {
                    int v = __hip_atomic_load(tslot + (lane & 31), __ATOMIC_RELAXED, __HIP_MEMORY_SCOPE_AGENT);
                    if (__all(v >= t)) break;
                    __builtin_amdgcn_s_sleep(1);
                }
            }
            __syncthreads();
            // stage h: 8 rows x 1024 packed uints = 2048 uint4; 16 per thread.
            // All 16 coherent loads issued back-to-back -> one round trip.
            const uint4v* hsrc16 = reinterpret_cast<const uint4v*>(
                hbuf + ((size_t)(t & 1) * B_SZ + b * MR) * D_SZ);
            uint4v vv[16];
#pragma unroll
            for (int i = 0; i < 16; i++) {
                asm volatile("global_load_dwordx4 %0, %1, off sc0 sc1"
                             : "=v"(vv[i]) : "v"(hsrc16 + tid + i * 128) : "memory");
            }
            asm volatile("s_waitcnt vmcnt(8)" ::: "memory");
            __builtin_amdgcn_sched_barrier(0);
#pragma unroll
            for (int i = 0; i < 8; i++) {
                int j   = tid + i * 128;            // uint4 index, 0..2047
                int row = j >> 8;                   // 256 uint4 per row
                int c4  = (j & 255) << 2;
                ushort4v hh, hl;
#pragma unroll
                for (int e = 0; e < 4; e++) {
                    unsigned int u = vv[i][e];      // hi | lo<<16
                    hh[e] = (unsigned short)(u & 0xFFFFu);
                    hl[e] = (unsigned short)(u >> 16);
                }
                *reinterpret_cast<ushort4v*>(&Hh[row][c4]) = hh;
                *reinterpret_cast<ushort4v*>(&Hl[row][c4]) = hl;
            }
            asm volatile("s_waitcnt vmcnt(0)" ::: "memory");
            __builtin_amdgcn_sched_barrier(0);
#pragma unroll
            for (int i = 8; i < 16; i++) {
                int j   = tid + i * 128;
                int row = j >> 8;
                int c4  = (j & 255) << 2;
                ushort4v hh, hl;
#pragma unroll
                for (int e = 0; e < 4; e++) {
                    unsigned int u = vv[i][e];
                    hh[e] = (unsigned short)(u & 0xFFFFu);
                    hl[e] = (unsigned short)(u >> 16);
                }
                *reinterpret_cast<ushort4v*>(&Hh[row][c4]) = hh;
                *reinterpret_cast<ushort4v*>(&Hl[row][c4]) = hl;
            }
            __syncthreads();
        }

        // S[0:16][16 cols] = H @ Wslice^T, 3 independent chains
        f32x4 a0 = (f32x4)0.0f, a1 = (f32x4)0.0f, a2 = (f32x4)0.0f;
#pragma unroll
        for (int kk = 0; kk < 32; kk++) {
            short8 ah  = *reinterpret_cast<const short8*>(&Hh[cl][kk * 32 + kb]);
            short8 alo = *reinterpret_cast<const short8*>(&Hl[cl][kk * 32 + kb]);
            short8 wlv = *reinterpret_cast<const short8*>(&Wlo[wave][cl][kk * 32 + kb]);
            a0 = __builtin_amdgcn_mfma_f32_16x16x32_bf16(ah,  wh[kk], a0, 0, 0, 0);
            a1 = __builtin_amdgcn_mfma_f32_16x16x32_bf16(alo, wh[kk], a1, 0, 0, 0);
            a2 = __builtin_amdgcn_mfma_f32_16x16x32_bf16(ah,  wlv,    a2, 0, 0, 0);
        }

        float hval[4];
        if (active) {
            unsigned int* hdst = hbuf + ((size_t)((t + 1) & 1) * B_SZ + b * MR) * D_SZ;
#pragma unroll
            for (int r = 0; r < 4; r++) {
                int row = rloc + r;
                float pre = (a0[r] + a1[r] + a2[r]) + xv[r] + bias;
                float h = tanhf(pre);
                hval[r] = h;
                unsigned short hh_, ll_;
                split2p(h, &hh_, &ll_);
                unsigned int packed = (unsigned int)hh_ | ((unsigned int)ll_ << 16);
                __hip_atomic_store(&hdst[(size_t)row * D_SZ + colg], packed,
                                   __ATOMIC_RELAXED, __HIP_MEMORY_SCOPE_AGENT);
            }
        }
        // drain the sc1 h-stores to the coherence point, then publish.
        asm volatile("s_waitcnt vmcnt(0)" ::: "memory");
        __syncthreads();
        if (tid == 0)
            __hip_atomic_store(tslot + c, t + 1, __ATOMIC_RELAXED, __HIP_MEMORY_SCOPE_AGENT);

        // out stores AFTER publish: off the inter-team critical path
        if (active) {
            float* outt = out + ((size_t)t * B_SZ + b * MR) * D_SZ;
#pragma unroll
            for (int r = 0; r < 4; r++) {
                int row = rloc + r;
                outt[(size_t)row * D_SZ + colg] = hval[r];
                if (t == T_LEN - 1)
                    out[(size_t)T_LEN * B_SZ * D_SZ + (size_t)(b * MR + row) * D_SZ + colg] = hval[r];
            }
        }
    }
}

// ---------------------------------------------------------------------------
extern "C" void kernel_launch(void* const* d_in, const int* in_sizes, int n_in,
                              void* d_out, int out_size, void* d_ws, size_t ws_size,
                              hipStream_t stream)
{
    const float* x   = (const float*)d_in[0];
    const float* Wih = (const float*)d_in[1];
    const float* Whh = (const float*)d_in[2];
    const float* bih = (const float*)d_in[3];
    const float* bhh = (const float*)d_in[4];
    float* out = (float*)d_out;

    char* ws = (char*)d_ws;
    float*        xp   = (float*)ws;                        // 134217728 B
    unsigned int* hbuf = (unsigned int*)(ws + 134217728);   // 524288 B
    int*          slot = (int*)(ws + 134217728 + 524288);   // 512 ints

    init_kernel<<<dim3(1), dim3(512), 0, stream>>>(slot);
    xproj_kernel<<<dim3(2048), dim3(256), 0, stream>>>(x, Wih, bih, xp);
    rnn_kernel<<<dim3(256), dim3(128), 0, stream>>>(xp, Whh, bhh, out, hbuf, slot);
}